// Round 3
// baseline (1035.059 us; speedup 1.0000x reference)
//
#include <hip/hip_runtime.h>
#include <hip/hip_bf16.h>

#define D 128
#define FEPS 1e-15f
#define PROJ_EPS 1e-5f

__device__ __forceinline__ float wave_sum64(float v) {
#pragma unroll
    for (int o = 32; o > 0; o >>= 1) v += __shfl_xor(v, o, 64);
    return v;
}

// ---- bias point: b = proj(exp_map_zero(bias_vec)); also y2 = ||b||^2 ----
__global__ void k_bias(const float* __restrict__ bias, float* __restrict__ bvec,
                       float* __restrict__ y2out) {
    int l = threadIdx.x;          // 64 threads, lane l handles d=l and d=l+64
    float b0 = bias[l], b1 = bias[64 + l];
    float n2 = wave_sum64(b0 * b0 + b1 * b1);
    float n = fmaxf(sqrtf(n2), FEPS);
    float t = tanhf(fminf(n, 15.f));
    float s = t / n;                       // exp-map scale
    float en2 = s * s * n2;                // ||e||^2
    float pn = fmaxf(sqrtf(en2), FEPS);
    float ps = fminf(1.f, (1.f - PROJ_EPS) / pn);
    float sc = s * ps;
    bvec[l] = b0 * sc;
    bvec[64 + l] = b1 * sc;
    if (l == 0) y2out[0] = ps * ps * en2;
}

// ---- fused log_map_zero + (tangent @ W), mapped stored bf16 ----
// block: 256 threads, 128 rows per block (16 passes x 8 rows)
__global__ __launch_bounds__(256) void k_logmap_gemm(
    const float* __restrict__ x, const float* __restrict__ W,
    __hip_bfloat16* __restrict__ mapped, int N)
{
    __shared__ unsigned int Wp[64 * 128];   // [kpair][d], 2 bf16 packed per uint
    __shared__ float tn[8][128];            // 8 tangent rows per pass

    const int tid = threadIdx.x;
    const int d = tid & 127;
    const int g = tid >> 7;                 // 0/1: which 4-row group in FMA phase
    const int wv = tid >> 6, ln = tid & 63; // wave id / lane for staging

    // load W into LDS as packed bf16 (precision impact ~0.4% rel, fine)
    for (int i = tid; i < 64 * 128; i += 256) {
        int kk = i >> 7, dd = i & 127;
        float w0 = W[(2 * kk) * D + dd];
        float w1 = W[(2 * kk + 1) * D + dd];
        __hip_bfloat16 h0 = __float2bfloat16(w0);
        __hip_bfloat16 h1 = __float2bfloat16(w1);
        unsigned u0 = *reinterpret_cast<unsigned short*>(&h0);
        unsigned u1 = *reinterpret_cast<unsigned short*>(&h1);
        Wp[i] = u0 | (u1 << 16);
    }
    __syncthreads();

    const int rowbase = blockIdx.x * 128;
    for (int pass = 0; pass < 16; ++pass) {
        const int base = rowbase + pass * 8;

        // stage 8 tangent rows: each wave computes 2 rows (norm via shfl)
#pragma unroll
        for (int j = 0; j < 2; ++j) {
            int row = base + 2 * wv + j;
            float x0 = 0.f, x1 = 0.f;
            if (row < N) { x0 = x[row * D + ln]; x1 = x[row * D + 64 + ln]; }
            float n2 = wave_sum64(x0 * x0 + x1 * x1);
            float n = fmaxf(sqrtf(n2), FEPS);
            float s = atanhf(fminf(n, 1.f - 1e-7f)) / n;
            tn[2 * wv + j][ln] = s * x0;
            tn[2 * wv + j][64 + ln] = s * x1;
        }
        __syncthreads();

        // FMA: thread computes column d for rows base+4g .. base+4g+3
        float acc0 = 0.f, acc1 = 0.f, acc2 = 0.f, acc3 = 0.f;
        const float* t0 = tn[4 * g + 0];
        const float* t1 = tn[4 * g + 1];
        const float* t2 = tn[4 * g + 2];
        const float* t3 = tn[4 * g + 3];
#pragma unroll
        for (int kk = 0; kk < 64; kk += 2) {         // 4 k per iteration
            unsigned ua = Wp[kk * 128 + d];
            unsigned ub = Wp[(kk + 1) * 128 + d];
            float w0 = __uint_as_float(ua << 16);
            float w1 = __uint_as_float(ua & 0xffff0000u);
            float w2 = __uint_as_float(ub << 16);
            float w3 = __uint_as_float(ub & 0xffff0000u);
            float4 a0 = *reinterpret_cast<const float4*>(&t0[2 * kk]);
            float4 a1 = *reinterpret_cast<const float4*>(&t1[2 * kk]);
            float4 a2 = *reinterpret_cast<const float4*>(&t2[2 * kk]);
            float4 a3 = *reinterpret_cast<const float4*>(&t3[2 * kk]);
            acc0 += a0.x * w0 + a0.y * w1 + a0.z * w2 + a0.w * w3;
            acc1 += a1.x * w0 + a1.y * w1 + a1.z * w2 + a1.w * w3;
            acc2 += a2.x * w0 + a2.y * w1 + a2.z * w2 + a2.w * w3;
            acc3 += a3.x * w0 + a3.y * w1 + a3.z * w2 + a3.w * w3;
        }
        int r0 = base + 4 * g;
        if (r0 + 0 < N) mapped[(r0 + 0) * D + d] = __float2bfloat16(acc0);
        if (r0 + 1 < N) mapped[(r0 + 1) * D + d] = __float2bfloat16(acc1);
        if (r0 + 2 < N) mapped[(r0 + 2) * D + d] = __float2bfloat16(acc2);
        if (r0 + 3 < N) mapped[(r0 + 3) * D + d] = __float2bfloat16(acc3);
        __syncthreads();   // tn reused next pass
    }
}

// ---- scatter-add aggregation: agg[row] += val * mapped[col] ----
// one thread per (edge, column-pair)
__global__ __launch_bounds__(256) void k_agg(
    const __hip_bfloat16* __restrict__ mapped, const float* __restrict__ val,
    const int* __restrict__ rowi, const int* __restrict__ coli,
    float* __restrict__ agg, int E)
{
    long long gid = (long long)blockIdx.x * 256 + threadIdx.x;
    int e = (int)(gid >> 6);
    if (e >= E) return;
    int dp = ((int)gid & 63) * 2;
    int r = rowi[e], c = coli[e];
    float v = val[e];
    unsigned u = *reinterpret_cast<const unsigned*>(&mapped[c * D + dp]);
    float m0 = __uint_as_float(u << 16);
    float m1 = __uint_as_float(u & 0xffff0000u);
    atomicAdd(&agg[r * D + dp], v * m0);
    atomicAdd(&agg[r * D + dp + 1], v * m1);
}

// ---- fused: h=proj(expmap(agg)); out=proj(mobius(h,b)); f32 store ----
// one wave per row, 4 rows per block; overwrites d_out (mapped is dead now)
__global__ __launch_bounds__(256) void k_finalize(
    const float* __restrict__ agg, const float* __restrict__ bvec,
    const float* __restrict__ y2p, float* __restrict__ out, int N)
{
    int wv = threadIdx.x >> 6, ln = threadIdx.x & 63;
    int row = blockIdx.x * 4 + wv;
    if (row >= N) return;
    float a0 = agg[row * D + ln], a1 = agg[row * D + 64 + ln];
    float b0 = bvec[ln], b1 = bvec[64 + ln];
    float y2 = y2p[0];

    // exp_map_zero + projection
    float n2 = wave_sum64(a0 * a0 + a1 * a1);
    float n = fmaxf(sqrtf(n2), FEPS);
    float t = tanhf(fminf(n, 15.f));
    float s = t / n;
    float en2 = s * s * n2;
    float pn = fmaxf(sqrtf(en2), FEPS);
    float ps = fminf(1.f, (1.f - PROJ_EPS) / pn);
    float hs = s * ps;
    float h0 = hs * a0, h1 = hs * a1;
    float x2 = ps * ps * en2;

    // mobius_addition(h, b)
    float xy = wave_sum64(h0 * b0 + h1 * b1);
    float cA = 1.f + 2.f * xy + y2;
    float cB = 1.f - x2;
    float den = fmaxf(1.f + 2.f * xy + x2 * y2, FEPS);
    float inv = 1.f / den;
    float z0 = (cA * h0 + cB * b0) * inv;
    float z1 = (cA * h1 + cB * b1) * inv;

    // final projection
    float zn2 = wave_sum64(z0 * z0 + z1 * z1);
    float zn = fmaxf(sqrtf(zn2), FEPS);
    float zs = fminf(1.f, (1.f - PROJ_EPS) / zn);
    out[row * D + ln] = z0 * zs;
    out[row * D + 64 + ln] = z1 * zs;
}

extern "C" void kernel_launch(void* const* d_in, const int* in_sizes, int n_in,
                              void* d_out, int out_size, void* d_ws, size_t ws_size,
                              hipStream_t stream) {
    const float* x    = (const float*)d_in[0];
    const float* W    = (const float*)d_in[1];
    const float* bias = (const float*)d_in[2];
    const float* val  = (const float*)d_in[3];
    const int*   rowi = (const int*)d_in[4];
    const int*   coli = (const int*)d_in[5];
    const int N = in_sizes[0] / D;
    const int E = in_sizes[3];

    // ws layout: bvec/y2 first, then agg. total = 1KB + 51.2MB
    char* ws = (char*)d_ws;
    float* bvec = (float*)ws;                 // 128 f32
    float* y2p  = bvec + D;                   // 1 f32
    float* agg  = (float*)(ws + 1024);        // N*128 f32 (51.2 MB)

    // d_out is N*D f32 = 51.2 MB. Stage bf16 `mapped` (25.6 MB) in its
    // SECOND half; dead after k_agg; k_finalize then overwrites all of d_out.
    float* out = (float*)d_out;
    __hip_bfloat16* mapped = (__hip_bfloat16*)((char*)d_out + (size_t)N * D * 2);

    hipMemsetAsync(agg, 0, (size_t)N * D * sizeof(float), stream);
    k_bias<<<1, 64, 0, stream>>>(bias, bvec, y2p);

    int gblocks = (N + 127) / 128;
    k_logmap_gemm<<<gblocks, 256, 0, stream>>>(x, W, mapped, N);

    long long aggthreads = (long long)E * 64;
    int ablocks = (int)((aggthreads + 255) / 256);
    k_agg<<<ablocks, 256, 0, stream>>>(mapped, val, rowi, coli, agg, E);

    k_finalize<<<(N + 3) / 4, 256, 0, stream>>>(agg, bvec, y2p, out, N);
}

// Round 4
// 221.830 us; speedup vs baseline: 4.6660x; 4.6660x over previous
//
#include <hip/hip_runtime.h>
#include <hip/hip_bf16.h>

#define D 128
#define FEPS 1e-15f
#define PROJ_EPS 1e-5f

typedef __attribute__((ext_vector_type(8))) short short8v;
typedef __attribute__((ext_vector_type(4))) float f32x4;

__device__ __forceinline__ float wave_sum64(float v) {
#pragma unroll
    for (int o = 32; o > 0; o >>= 1) v += __shfl_xor(v, o, 64);
    return v;
}

__device__ __forceinline__ unsigned pack_bf16x2(float lo, float hi) {
    __hip_bfloat16 h0 = __float2bfloat16(lo);
    __hip_bfloat16 h1 = __float2bfloat16(hi);
    unsigned u0 = *reinterpret_cast<unsigned short*>(&h0);
    unsigned u1 = *reinterpret_cast<unsigned short*>(&h1);
    return u0 | (u1 << 16);
}

// ---- bias point: b = proj(exp_map_zero(bias_vec)); also y2 = ||b||^2 ----
__global__ void k_bias(const float* __restrict__ bias, float* __restrict__ bvec,
                       float* __restrict__ y2out) {
    int l = threadIdx.x;
    float b0 = bias[l], b1 = bias[64 + l];
    float n2 = wave_sum64(b0 * b0 + b1 * b1);
    float n = fmaxf(sqrtf(n2), FEPS);
    float t = tanhf(fminf(n, 15.f));
    float s = t / n;
    float en2 = s * s * n2;
    float pn = fmaxf(sqrtf(en2), FEPS);
    float ps = fminf(1.f, (1.f - PROJ_EPS) / pn);
    float sc = s * ps;
    bvec[l] = b0 * sc;
    bvec[64 + l] = b1 * sc;
    if (l == 0) y2out[0] = ps * ps * en2;
}

// ---- MFMA GEMM: mapped = (logmap(x)) @ W, bf16 out ----
// 64 rows/block, 4 waves (16 rows each). LDS: W^T 32KB + A 16KB, XOR-swizzled.
__global__ __launch_bounds__(256) void k_gemm(
    const float* __restrict__ x, const float* __restrict__ W,
    __hip_bfloat16* __restrict__ mapped, int Nn)
{
    __shared__ unsigned lsW[128 * 64];   // [col][kpair], swizzled
    __shared__ unsigned lsA[64 * 64];    // [row][kpair], swizzled

    const int tid = threadIdx.x;
    const int w = tid >> 6, l = tid & 63;

    // stage W^T (bf16 pairs), coalesced read, swizzled LDS write
    for (int i = tid; i < 128 * 64; i += 256) {
        int col = i & 127, kp = i >> 7;
        float w0 = W[(2 * kp) * D + col];
        float w1 = W[(2 * kp + 1) * D + col];
        int byt = (kp * 4) ^ ((col & 7) << 4);
        lsW[col * 64 + (byt >> 2)] = pack_bf16x2(w0, w1);
    }

    // stage A: each wave computes+writes its own 16 rows (log-map fused)
    const int rowbase = blockIdx.x * 64;
#pragma unroll 1
    for (int i = 0; i < 16; ++i) {
        int rl = w * 16 + i;
        int row = rowbase + rl;
        float2 xv = make_float2(0.f, 0.f);
        if (row < Nn) xv = *reinterpret_cast<const float2*>(&x[row * D + 2 * l]);
        float n2 = wave_sum64(xv.x * xv.x + xv.y * xv.y);
        float n = fmaxf(sqrtf(n2), FEPS);
        float s = atanhf(fminf(n, 1.f - 1e-7f)) / n;
        int byt = (4 * l) ^ ((rl & 7) << 4);
        lsA[rl * 64 + (byt >> 2)] = pack_bf16x2(s * xv.x, s * xv.y);
    }
    __syncthreads();   // for lsW (lsA is wave-private)

    f32x4 acc[8];
#pragma unroll
    for (int n = 0; n < 8; ++n) acc[n] = (f32x4){0.f, 0.f, 0.f, 0.f};

    const char* cA = (const char*)lsA;
    const char* cW = (const char*)lsW;
    const int r16 = l & 15, khi = l >> 4;
    const int swz = (r16 & 7) << 4;
#pragma unroll
    for (int ks = 0; ks < 4; ++ks) {
        int koff = ks * 64 + khi * 16;
        short8v a = *(const short8v*)(cA + (w * 16 + r16) * 256 + ((koff ^ swz)));
#pragma unroll
        for (int n = 0; n < 8; ++n) {
            short8v b = *(const short8v*)(cW + (n * 16 + r16) * 256 + ((koff ^ swz)));
            acc[n] = __builtin_amdgcn_mfma_f32_16x16x32_bf16(a, b, acc[n], 0, 0, 0);
        }
    }

    // D layout: col = l&15, row = (l>>4)*4 + r
#pragma unroll
    for (int n = 0; n < 8; ++n) {
#pragma unroll
        for (int r = 0; r < 4; ++r) {
            int row = rowbase + w * 16 + khi * 4 + r;
            if (row < Nn) mapped[row * D + n * 16 + r16] = __float2bfloat16(acc[n][r]);
        }
    }
}

// ---- CSR build ----
__global__ __launch_bounds__(256) void k_hist(const int* __restrict__ rowi,
                                              int* __restrict__ cnt, int E) {
    int e = blockIdx.x * 256 + threadIdx.x;
    if (e < E) atomicAdd(&cnt[rowi[e]], 1);
}

// block-local exclusive scan: 256 threads x 4 elems = 1024/block
__global__ __launch_bounds__(256) void k_scan1(const int* __restrict__ cnt,
                                               int* __restrict__ ex,
                                               int* __restrict__ bsum, int Nn) {
    __shared__ int ts[256];
    int t = threadIdx.x, b = blockIdx.x;
    int base = b * 1024 + t * 4;
    int v0 = (base + 0 < Nn) ? cnt[base + 0] : 0;
    int v1 = (base + 1 < Nn) ? cnt[base + 1] : 0;
    int v2 = (base + 2 < Nn) ? cnt[base + 2] : 0;
    int v3 = (base + 3 < Nn) ? cnt[base + 3] : 0;
    int s = v0 + v1 + v2 + v3;
    ts[t] = s;
    __syncthreads();
    for (int off = 1; off < 256; off <<= 1) {
        int add = (t >= off) ? ts[t - off] : 0;
        __syncthreads();
        ts[t] += add;
        __syncthreads();
    }
    int excl = ts[t] - s;
    if (t == 255) bsum[b] = ts[t];
    if (base + 0 < Nn) ex[base + 0] = excl;
    if (base + 1 < Nn) ex[base + 1] = excl + v0;
    if (base + 2 < Nn) ex[base + 2] = excl + v0 + v1;
    if (base + 3 < Nn) ex[base + 3] = excl + v0 + v1 + v2;
}

__global__ void k_scan2(const int* __restrict__ bsum, int* __restrict__ bsumx, int nb) {
    __shared__ int ts[128];
    int t = threadIdx.x;
    int v = (t < nb) ? bsum[t] : 0;
    ts[t] = v;
    __syncthreads();
    for (int off = 1; off < 128; off <<= 1) {
        int add = (t >= off) ? ts[t - off] : 0;
        __syncthreads();
        ts[t] += add;
        __syncthreads();
    }
    bsumx[t] = ts[t] - v;   // exclusive
}

__global__ __launch_bounds__(256) void k_scan3(int* __restrict__ rowptr,
                                               const int* __restrict__ bsumx,
                                               int* __restrict__ cursor, int Nn, int E) {
    int i = blockIdx.x * 256 + threadIdx.x;
    if (i < Nn) {
        int v = rowptr[i] + bsumx[i >> 10];
        rowptr[i] = v;
        cursor[i] = v;
    }
    if (i == 0) rowptr[Nn] = E;
}

__global__ __launch_bounds__(256) void k_scatter(
    const int* __restrict__ rowi, const int* __restrict__ coli,
    const float* __restrict__ val, int* __restrict__ cursor,
    int2* __restrict__ sedge, int E) {
    int e = blockIdx.x * 256 + threadIdx.x;
    if (e >= E) return;
    int r = rowi[e];
    int p = atomicAdd(&cursor[r], 1);
    sedge[p] = make_int2(coli[e], __float_as_int(val[e]));
}

// ---- fused: CSR gather-reduce + expmap + proj + mobius + proj, f32 out ----
// one wave per row; lane l owns dims 2l, 2l+1
__global__ __launch_bounds__(256) void k_aggfin(
    const unsigned* __restrict__ mapped, const int2* __restrict__ sedge,
    const int* __restrict__ rowptr, const float* __restrict__ bvec,
    const float* __restrict__ y2p, float* __restrict__ out, int Nn)
{
    int w = threadIdx.x >> 6, l = threadIdx.x & 63;
    int row = blockIdx.x * 4 + w;
    if (row >= Nn) return;
    int beg = rowptr[row], end = rowptr[row + 1];

    float a0 = 0.f, a1 = 0.f;
    for (int e = beg; e < end; ++e) {
        int2 ed = sedge[e];
        float v = __int_as_float(ed.y);
        unsigned u = mapped[ed.x * 64 + l];          // dims 2l, 2l+1 (bf16 pair)
        a0 += v * __uint_as_float(u << 16);
        a1 += v * __uint_as_float(u & 0xffff0000u);
    }

    float b0 = bvec[2 * l], b1 = bvec[2 * l + 1];
    float y2 = y2p[0];

    // exp_map_zero + projection
    float n2 = wave_sum64(a0 * a0 + a1 * a1);
    float n = fmaxf(sqrtf(n2), FEPS);
    float t = tanhf(fminf(n, 15.f));
    float s = t / n;
    float en2 = s * s * n2;
    float pn = fmaxf(sqrtf(en2), FEPS);
    float ps = fminf(1.f, (1.f - PROJ_EPS) / pn);
    float hs = s * ps;
    float h0 = hs * a0, h1 = hs * a1;
    float x2 = ps * ps * en2;

    // mobius_addition(h, b)
    float xy = wave_sum64(h0 * b0 + h1 * b1);
    float cA = 1.f + 2.f * xy + y2;
    float cB = 1.f - x2;
    float den = fmaxf(1.f + 2.f * xy + x2 * y2, FEPS);
    float inv = 1.f / den;
    float z0 = (cA * h0 + cB * b0) * inv;
    float z1 = (cA * h1 + cB * b1) * inv;

    // final projection
    float zn2 = wave_sum64(z0 * z0 + z1 * z1);
    float zn = fmaxf(sqrtf(zn2), FEPS);
    float zs = fminf(1.f, (1.f - PROJ_EPS) / zn);
    float2 o = make_float2(z0 * zs, z1 * zs);
    *reinterpret_cast<float2*>(&out[row * D + 2 * l]) = o;
}

extern "C" void kernel_launch(void* const* d_in, const int* in_sizes, int n_in,
                              void* d_out, int out_size, void* d_ws, size_t ws_size,
                              hipStream_t stream) {
    const float* x    = (const float*)d_in[0];
    const float* W    = (const float*)d_in[1];
    const float* bias = (const float*)d_in[2];
    const float* val  = (const float*)d_in[3];
    const int*   rowi = (const int*)d_in[4];
    const int*   coli = (const int*)d_in[5];
    const int N = in_sizes[0] / D;
    const int E = in_sizes[3];

    // ws layout (~32 MB; round-3 kernel proved ws >= 51.2 MB)
    char* ws = (char*)d_ws;
    float* bvec   = (float*)ws;                       // 512 B
    float* y2p    = (float*)(ws + 512);               // 4 B
    int*   cnt    = (int*)(ws + 1024);                // N*4
    int*   rowptr = (int*)(ws + 1024 + 400000);       // (N+1)*4
    int*   bsum   = (int*)(ws + 1024 + 800512);       // 128*4
    int*   bsumx  = (int*)(ws + 1024 + 801024);       // 128*4
    int*   cursor = (int*)(ws + 1024 + 801536);       // N*4
    int2*  sedge  = (int2*)(ws + 1024 + 1201536);     // E*8
    __hip_bfloat16* mapped = (__hip_bfloat16*)(ws + 1024 + 1201536 + (size_t)E * 8);  // N*D*2
    float* out = (float*)d_out;

    hipMemsetAsync(cnt, 0, (size_t)N * sizeof(int), stream);
    k_bias<<<1, 64, 0, stream>>>(bias, bvec, y2p);
    k_gemm<<<(N + 63) / 64, 256, 0, stream>>>(x, W, mapped, N);
    k_hist<<<(E + 255) / 256, 256, 0, stream>>>(rowi, cnt, E);
    int nb = (N + 1023) / 1024;
    k_scan1<<<nb, 256, 0, stream>>>(cnt, rowptr, bsum, N);
    k_scan2<<<1, 128, 0, stream>>>(bsum, bsumx, nb);
    k_scan3<<<(N + 255) / 256, 256, 0, stream>>>(rowptr, bsumx, cursor, N, E);
    k_scatter<<<(E + 255) / 256, 256, 0, stream>>>(rowi, coli, val, cursor, sedge, E);
    k_aggfin<<<(N + 3) / 4, 256, 0, stream>>>((const unsigned*)mapped, sedge, rowptr,
                                              bvec, y2p, out, N);
}

// Round 5
// 162.409 us; speedup vs baseline: 6.3732x; 1.3659x over previous
//
#include <hip/hip_runtime.h>
#include <hip/hip_bf16.h>

#define D 128
#define FEPS 1e-15f
#define PROJ_EPS 1e-5f

typedef __attribute__((ext_vector_type(8))) short short8v;
typedef __attribute__((ext_vector_type(4))) float f32x4;

__device__ __forceinline__ float wave_sum64(float v) {
#pragma unroll
    for (int o = 32; o > 0; o >>= 1) v += __shfl_xor(v, o, 64);
    return v;
}

__device__ __forceinline__ void wave_sum64_x2(float& p, float& q) {
#pragma unroll
    for (int o = 32; o > 0; o >>= 1) {
        p += __shfl_xor(p, o, 64);
        q += __shfl_xor(q, o, 64);
    }
}

__device__ __forceinline__ unsigned pack_bf16x2(float lo, float hi) {
    __hip_bfloat16 h0 = __float2bfloat16(lo);
    __hip_bfloat16 h1 = __float2bfloat16(hi);
    unsigned u0 = *reinterpret_cast<unsigned short*>(&h0);
    unsigned u1 = *reinterpret_cast<unsigned short*>(&h1);
    return u0 | (u1 << 16);
}

__device__ __forceinline__ float fast_tanh_clamped(float n) {
    // tanh(min(n,15)) for n >= 0
    float nc = fminf(n, 15.f);
    float e2 = __expf(2.f * nc);
    return 1.f - __fdividef(2.f, e2 + 1.f);
}

// ---- fused MFMA GEMM (mapped = logmap(x) @ W) + edge histogram ----
// blocks [0, GB): 128-row GEMM tiles, 8 waves; blocks [GB, GB+HB): histogram
__global__ __launch_bounds__(512) void k_gemm_hist(
    const float* __restrict__ x, const float* __restrict__ W,
    __hip_bfloat16* __restrict__ mapped, int Nn,
    const int* __restrict__ rowi, int* __restrict__ cnt, int E, int GB, int HB)
{
    __shared__ unsigned lsW[128 * 64];   // [col][kpair], swizzled (32 KB)
    __shared__ unsigned lsA[128 * 64];   // [row][kpair], swizzled (32 KB)

    const int tid = threadIdx.x;

    if (blockIdx.x >= GB) {
        // ---- histogram role ----
        int stride = HB * 512;
        for (int e = (blockIdx.x - GB) * 512 + tid; e < E; e += stride)
            atomicAdd(&cnt[rowi[e]], 1);
        return;
    }

    const int w = tid >> 6, l = tid & 63;

    // stage W^T (bf16 pairs), coalesced read, swizzled LDS write
    for (int i = tid; i < 128 * 64; i += 512) {
        int col = i & 127, kp = i >> 7;
        float w0 = W[(2 * kp) * D + col];
        float w1 = W[(2 * kp + 1) * D + col];
        int byt = (kp * 4) ^ ((col & 7) << 4);
        lsW[col * 64 + (byt >> 2)] = pack_bf16x2(w0, w1);
    }

    // stage A: each wave computes+writes its own 16 rows, 2 rows interleaved
    const int rowbase = blockIdx.x * 128;
#pragma unroll 1
    for (int i = 0; i < 16; i += 2) {
        int rl0 = w * 16 + i, rl1 = rl0 + 1;
        int row0 = rowbase + rl0, row1 = rowbase + rl1;
        float2 xv0 = make_float2(0.f, 0.f), xv1 = make_float2(0.f, 0.f);
        if (row0 < Nn) xv0 = *reinterpret_cast<const float2*>(&x[row0 * D + 2 * l]);
        if (row1 < Nn) xv1 = *reinterpret_cast<const float2*>(&x[row1 * D + 2 * l]);
        float n2a = xv0.x * xv0.x + xv0.y * xv0.y;
        float n2b = xv1.x * xv1.x + xv1.y * xv1.y;
        wave_sum64_x2(n2a, n2b);
        float na = fmaxf(sqrtf(n2a), FEPS);
        float nb = fmaxf(sqrtf(n2b), FEPS);
        float ca = fminf(na, 1.f - 1e-7f), cb = fminf(nb, 1.f - 1e-7f);
        float sa = __fdividef(0.5f * __logf(__fdividef(1.f + ca, 1.f - ca)), na);
        float sb = __fdividef(0.5f * __logf(__fdividef(1.f + cb, 1.f - cb)), nb);
        int bya = (4 * l) ^ ((rl0 & 7) << 4);
        int byb = (4 * l) ^ ((rl1 & 7) << 4);
        lsA[rl0 * 64 + (bya >> 2)] = pack_bf16x2(sa * xv0.x, sa * xv0.y);
        lsA[rl1 * 64 + (byb >> 2)] = pack_bf16x2(sb * xv1.x, sb * xv1.y);
    }
    __syncthreads();   // for lsW (lsA is wave-private)

    f32x4 acc[8];
#pragma unroll
    for (int n = 0; n < 8; ++n) acc[n] = (f32x4){0.f, 0.f, 0.f, 0.f};

    const char* cA = (const char*)lsA;
    const char* cW = (const char*)lsW;
    const int r16 = l & 15, khi = l >> 4;
    const int swz = (r16 & 7) << 4;
#pragma unroll
    for (int ks = 0; ks < 4; ++ks) {
        int koff = ks * 64 + khi * 16;
        short8v a = *(const short8v*)(cA + (w * 16 + r16) * 256 + (koff ^ swz));
#pragma unroll
        for (int n = 0; n < 8; ++n) {
            short8v b = *(const short8v*)(cW + (n * 16 + r16) * 256 + (koff ^ swz));
            acc[n] = __builtin_amdgcn_mfma_f32_16x16x32_bf16(a, b, acc[n], 0, 0, 0);
        }
    }

    // D layout: col = l&15, row = khi*4 + r (within wave's 16-row sub-tile)
#pragma unroll
    for (int n = 0; n < 8; ++n) {
#pragma unroll
        for (int r = 0; r < 4; ++r) {
            int row = rowbase + w * 16 + khi * 4 + r;
            if (row < Nn) mapped[row * D + n * 16 + r16] = __float2bfloat16(acc[n][r]);
        }
    }
}

// ---- CSR scan chain ----
__global__ __launch_bounds__(256) void k_scan1(const int* __restrict__ cnt,
                                               int* __restrict__ ex,
                                               int* __restrict__ bsum, int Nn) {
    __shared__ int ts[256];
    int t = threadIdx.x, b = blockIdx.x;
    int base = b * 1024 + t * 4;
    int v0 = (base + 0 < Nn) ? cnt[base + 0] : 0;
    int v1 = (base + 1 < Nn) ? cnt[base + 1] : 0;
    int v2 = (base + 2 < Nn) ? cnt[base + 2] : 0;
    int v3 = (base + 3 < Nn) ? cnt[base + 3] : 0;
    int s = v0 + v1 + v2 + v3;
    ts[t] = s;
    __syncthreads();
    for (int off = 1; off < 256; off <<= 1) {
        int add = (t >= off) ? ts[t - off] : 0;
        __syncthreads();
        ts[t] += add;
        __syncthreads();
    }
    int excl = ts[t] - s;
    if (t == 255) bsum[b] = ts[t];
    if (base + 0 < Nn) ex[base + 0] = excl;
    if (base + 1 < Nn) ex[base + 1] = excl + v0;
    if (base + 2 < Nn) ex[base + 2] = excl + v0 + v1;
    if (base + 3 < Nn) ex[base + 3] = excl + v0 + v1 + v2;
}

__global__ void k_scan2(const int* __restrict__ bsum, int* __restrict__ bsumx, int nb) {
    __shared__ int ts[128];
    int t = threadIdx.x;
    int v = (t < nb) ? bsum[t] : 0;
    ts[t] = v;
    __syncthreads();
    for (int off = 1; off < 128; off <<= 1) {
        int add = (t >= off) ? ts[t - off] : 0;
        __syncthreads();
        ts[t] += add;
        __syncthreads();
    }
    bsumx[t] = ts[t] - v;   // exclusive
}

__global__ __launch_bounds__(256) void k_scan3(int* __restrict__ rowptr,
                                               const int* __restrict__ bsumx,
                                               int* __restrict__ cursor, int Nn, int E) {
    int i = blockIdx.x * 256 + threadIdx.x;
    if (i < Nn) {
        int v = rowptr[i] + bsumx[i >> 10];
        rowptr[i] = v;
        cursor[i] = v;
    }
    if (i == 0) rowptr[Nn] = E;
}

__global__ __launch_bounds__(256) void k_scatter(
    const int* __restrict__ rowi, const int* __restrict__ coli,
    const float* __restrict__ val, int* __restrict__ cursor,
    int2* __restrict__ sedge, int E) {
    int e = blockIdx.x * 256 + threadIdx.x;
    if (e >= E) return;
    int r = rowi[e];
    int p = atomicAdd(&cursor[r], 1);
    sedge[p] = make_int2(coli[e], __float_as_int(val[e]));
}

// ---- fused: bias + CSR gather-reduce + expmap + proj + mobius + proj ----
// one wave per row; lane l owns dims 2l, 2l+1
__global__ __launch_bounds__(256) void k_aggfin(
    const unsigned* __restrict__ mapped, const int2* __restrict__ sedge,
    const int* __restrict__ rowptr, const float* __restrict__ bias,
    float* __restrict__ out, int Nn)
{
    int w = threadIdx.x >> 6, l = threadIdx.x & 63;
    int row = blockIdx.x * 4 + w;
    if (row >= Nn) return;

    // bias point (per-wave recompute: ~60 cy, saves a kernel launch + ws dep)
    float2 rb = *reinterpret_cast<const float2*>(&bias[2 * l]);
    float bn2 = wave_sum64(rb.x * rb.x + rb.y * rb.y);
    float bn = fmaxf(sqrtf(bn2), FEPS);
    float bt = fast_tanh_clamped(bn);
    float bs = __fdividef(bt, bn);
    float ben2 = bs * bs * bn2;
    float bpn = fmaxf(sqrtf(ben2), FEPS);
    float bps = fminf(1.f, __fdividef(1.f - PROJ_EPS, bpn));
    float bsc = bs * bps;
    float b0 = rb.x * bsc, b1 = rb.y * bsc;
    float y2 = bps * bps * ben2;

    int beg = rowptr[row], end = rowptr[row + 1];
    const unsigned* mp = mapped + l;

    // 2-wide unrolled gather-reduce (two independent dependency chains)
    float a0 = 0.f, a1 = 0.f, c0 = 0.f, c1 = 0.f;
    int e = beg;
    for (; e + 1 < end; e += 2) {
        int2 d0 = sedge[e];
        int2 d1 = sedge[e + 1];
        unsigned u0 = mp[d0.x * 64];
        unsigned u1 = mp[d1.x * 64];
        float v0 = __int_as_float(d0.y), v1 = __int_as_float(d1.y);
        a0 += v0 * __uint_as_float(u0 << 16);
        a1 += v0 * __uint_as_float(u0 & 0xffff0000u);
        c0 += v1 * __uint_as_float(u1 << 16);
        c1 += v1 * __uint_as_float(u1 & 0xffff0000u);
    }
    if (e < end) {
        int2 d0 = sedge[e];
        unsigned u0 = mp[d0.x * 64];
        float v0 = __int_as_float(d0.y);
        a0 += v0 * __uint_as_float(u0 << 16);
        a1 += v0 * __uint_as_float(u0 & 0xffff0000u);
    }
    a0 += c0; a1 += c1;

    // dual reduction: n2 = sum a^2, ab = sum a.b  (one shfl chain)
    float n2 = a0 * a0 + a1 * a1;
    float ab = a0 * b0 + a1 * b1;
    wave_sum64_x2(n2, ab);

    // exp_map_zero + projection (scalars all wave-uniform)
    float n = fmaxf(sqrtf(n2), FEPS);
    float t = fast_tanh_clamped(n);
    float s = __fdividef(t, n);
    float en2 = s * s * n2;
    float pn = fmaxf(sqrtf(en2), FEPS);
    float ps = fminf(1.f, __fdividef(1.f - PROJ_EPS, pn));
    float hs = s * ps;
    float x2 = ps * ps * en2;

    // mobius_addition + final projection, |z|^2 computed analytically
    float xy = hs * ab;
    float cA = 1.f + 2.f * xy + y2;
    float cB = 1.f - x2;
    float den = fmaxf(1.f + 2.f * xy + x2 * y2, FEPS);
    float inv = __fdividef(1.f, den);
    float zn2 = inv * inv * (cA * cA * x2 + 2.f * cA * cB * xy + cB * cB * y2);
    float zn = fmaxf(sqrtf(zn2), FEPS);
    float zs = fminf(1.f, __fdividef(1.f - PROJ_EPS, zn));
    float f = inv * zs;
    float chs = cA * hs;
    float2 o = make_float2((chs * a0 + cB * b0) * f, (chs * a1 + cB * b1) * f);
    *reinterpret_cast<float2*>(&out[row * D + 2 * l]) = o;
}

extern "C" void kernel_launch(void* const* d_in, const int* in_sizes, int n_in,
                              void* d_out, int out_size, void* d_ws, size_t ws_size,
                              hipStream_t stream) {
    const float* x    = (const float*)d_in[0];
    const float* W    = (const float*)d_in[1];
    const float* bias = (const float*)d_in[2];
    const float* val  = (const float*)d_in[3];
    const int*   rowi = (const int*)d_in[4];
    const int*   coli = (const int*)d_in[5];
    const int N = in_sizes[0] / D;
    const int E = in_sizes[3];

    // ws layout (~32 MB)
    char* ws = (char*)d_ws;
    int*   cnt    = (int*)ws;                         // N*4
    int*   rowptr = (int*)(ws + 400000);              // (N+1)*4
    int*   bsum   = (int*)(ws + 800512);              // 128*4
    int*   bsumx  = (int*)(ws + 801024);              // 128*4
    int*   cursor = (int*)(ws + 801536);              // N*4
    int2*  sedge  = (int2*)(ws + 1201536);            // E*8
    __hip_bfloat16* mapped = (__hip_bfloat16*)(ws + 1201536 + (size_t)E * 8);  // N*D*2
    float* out = (float*)d_out;

    hipMemsetAsync(cnt, 0, (size_t)N * sizeof(int), stream);

    const int GB = (N + 127) / 128;     // gemm blocks (128 rows each)
    const int HB = 256;                 // histogram blocks
    k_gemm_hist<<<GB + HB, 512, 0, stream>>>(x, W, mapped, N, rowi, cnt, E, GB, HB);

    int nb = (N + 1023) / 1024;
    k_scan1<<<nb, 256, 0, stream>>>(cnt, rowptr, bsum, N);
    k_scan2<<<1, 128, 0, stream>>>(bsum, bsumx, nb);
    k_scan3<<<(N + 255) / 256, 256, 0, stream>>>(rowptr, bsumx, cursor, N, E);
    k_scatter<<<(E + 255) / 256, 256, 0, stream>>>(rowi, coli, val, cursor, sedge, E);
    k_aggfin<<<(N + 3) / 4, 256, 0, stream>>>((const unsigned*)mapped, sedge, rowptr,
                                              bias, out, N);
}

// Round 6
// 162.389 us; speedup vs baseline: 6.3739x; 1.0001x over previous
//
#include <hip/hip_runtime.h>
#include <hip/hip_bf16.h>

#define D 128
#define FEPS 1e-15f
#define PROJ_EPS 1e-5f

typedef __attribute__((ext_vector_type(8))) short short8v;
typedef __attribute__((ext_vector_type(4))) float f32x4;

__device__ __forceinline__ unsigned pack_bf16x2(float lo, float hi) {
    __hip_bfloat16 h0 = __float2bfloat16(lo);
    __hip_bfloat16 h1 = __float2bfloat16(hi);
    unsigned u0 = *reinterpret_cast<unsigned short*>(&h0);
    unsigned u1 = *reinterpret_cast<unsigned short*>(&h1);
    return u0 | (u1 << 16);
}

__device__ __forceinline__ float bf_lo(unsigned u) { return __uint_as_float(u << 16); }
__device__ __forceinline__ float bf_hi(unsigned u) { return __uint_as_float(u & 0xffff0000u); }

__device__ __forceinline__ float fast_tanh_clamped(float n) {
    float nc = fminf(n, 15.f);
    float e2 = __expf(2.f * nc);
    return 1.f - __fdividef(2.f, e2 + 1.f);
}

// ---- edge histogram ----
__global__ __launch_bounds__(512) void k_hist(const int* __restrict__ rowi,
                                              int* __restrict__ cnt, int E) {
    int e = blockIdx.x * 512 + threadIdx.x;
    if (e < E) atomicAdd(&cnt[rowi[e]], 1);
}

// ---- CSR scan chain ----
__global__ __launch_bounds__(256) void k_scan1(const int* __restrict__ cnt,
                                               int* __restrict__ ex,
                                               int* __restrict__ bsum, int Nn) {
    __shared__ int ts[256];
    int t = threadIdx.x, b = blockIdx.x;
    int base = b * 1024 + t * 4;
    int v0 = (base + 0 < Nn) ? cnt[base + 0] : 0;
    int v1 = (base + 1 < Nn) ? cnt[base + 1] : 0;
    int v2 = (base + 2 < Nn) ? cnt[base + 2] : 0;
    int v3 = (base + 3 < Nn) ? cnt[base + 3] : 0;
    int s = v0 + v1 + v2 + v3;
    ts[t] = s;
    __syncthreads();
    for (int off = 1; off < 256; off <<= 1) {
        int add = (t >= off) ? ts[t - off] : 0;
        __syncthreads();
        ts[t] += add;
        __syncthreads();
    }
    int excl = ts[t] - s;
    if (t == 255) bsum[b] = ts[t];
    if (base + 0 < Nn) ex[base + 0] = excl;
    if (base + 1 < Nn) ex[base + 1] = excl + v0;
    if (base + 2 < Nn) ex[base + 2] = excl + v0 + v1;
    if (base + 3 < Nn) ex[base + 3] = excl + v0 + v1 + v2;
}

__global__ void k_scan2(const int* __restrict__ bsum, int* __restrict__ bsumx, int nb) {
    __shared__ int ts[128];
    int t = threadIdx.x;
    int v = (t < nb) ? bsum[t] : 0;
    ts[t] = v;
    __syncthreads();
    for (int off = 1; off < 128; off <<= 1) {
        int add = (t >= off) ? ts[t - off] : 0;
        __syncthreads();
        ts[t] += add;
        __syncthreads();
    }
    bsumx[t] = ts[t] - v;   // exclusive
}

__global__ __launch_bounds__(256) void k_scan3(int* __restrict__ rowptr,
                                               const int* __restrict__ bsumx,
                                               int* __restrict__ cursor, int Nn, int E) {
    int i = blockIdx.x * 256 + threadIdx.x;
    if (i < Nn) {
        int v = rowptr[i] + bsumx[i >> 10];
        rowptr[i] = v;
        cursor[i] = v;
    }
    if (i == 0) rowptr[Nn] = E;
}

// ---- fused MFMA GEMM (mapped = logmap(x) @ W) + edge scatter ----
// blocks [0,GB): 128-row GEMM tiles, 8 waves, A-fragments built in registers;
// blocks [GB,GB+SB): CSR scatter (overlaps with GEMM).
__global__ __launch_bounds__(512) void k_gemm_scatter(
    const float* __restrict__ x, const float* __restrict__ W,
    __hip_bfloat16* __restrict__ mapped, int Nn,
    const int* __restrict__ rowi, const int* __restrict__ coli,
    const float* __restrict__ val, int* __restrict__ cursor,
    int2* __restrict__ sedge, int E, int GB, int SB)
{
    __shared__ unsigned lsW[128 * 64];   // [col][kpair], swizzled (32 KB)

    const int tid = threadIdx.x;

    if (blockIdx.x >= GB) {
        // ---- scatter role ----
        int stride = SB * 512;
        for (int e = (blockIdx.x - GB) * 512 + tid; e < E; e += stride) {
            int r = rowi[e];
            int p = atomicAdd(&cursor[r], 1);
            sedge[p] = make_int2(coli[e], __float_as_int(val[e]));
        }
        return;
    }

    const int w = tid >> 6, l = tid & 63;
    const int q = l & 15, khi = l >> 4;

    // stage W^T (bf16 pairs), coalesced read, swizzled LDS write
    for (int i = tid; i < 128 * 64; i += 512) {
        int col = i & 127, kp = i >> 7;
        float w0 = W[(2 * kp) * D + col];
        float w1 = W[(2 * kp + 1) * D + col];
        int byt = (kp * 4) ^ ((col & 7) << 4);
        lsW[col * 64 + (byt >> 2)] = pack_bf16x2(w0, w1);
    }

    // A-fragments direct to registers: lane l = row q, k = ks*32 + khi*8 + j
    const int row = blockIdx.x * 128 + w * 16 + q;
    const bool rv = row < Nn;
    const float* xr = x + (size_t)row * D;
    float4 xa[8];
    float nn = 0.f;
#pragma unroll
    for (int ks = 0; ks < 4; ++ks) {
        float4 p0 = make_float4(0.f, 0.f, 0.f, 0.f), p1 = p0;
        if (rv) {
            p0 = *reinterpret_cast<const float4*>(xr + ks * 32 + khi * 8);
            p1 = *reinterpret_cast<const float4*>(xr + ks * 32 + khi * 8 + 4);
        }
        xa[2 * ks] = p0; xa[2 * ks + 1] = p1;
        nn += p0.x * p0.x + p0.y * p0.y + p0.z * p0.z + p0.w * p0.w
            + p1.x * p1.x + p1.y * p1.y + p1.z * p1.z + p1.w * p1.w;
    }
    nn += __shfl_xor(nn, 16, 64);
    nn += __shfl_xor(nn, 32, 64);           // full 128-dim row norm^2
    float n = fmaxf(sqrtf(nn), FEPS);
    float c = fminf(n, 1.f - 1e-7f);
    float s = __fdividef(0.5f * __logf(__fdividef(1.f + c, 1.f - c)), n);

    union { unsigned u[4]; short8v v; } af[4];
#pragma unroll
    for (int ks = 0; ks < 4; ++ks) {
        float4 p0 = xa[2 * ks], p1 = xa[2 * ks + 1];
        af[ks].u[0] = pack_bf16x2(s * p0.x, s * p0.y);
        af[ks].u[1] = pack_bf16x2(s * p0.z, s * p0.w);
        af[ks].u[2] = pack_bf16x2(s * p1.x, s * p1.y);
        af[ks].u[3] = pack_bf16x2(s * p1.z, s * p1.w);
    }
    __syncthreads();   // lsW ready

    f32x4 acc[8];
#pragma unroll
    for (int t = 0; t < 8; ++t) acc[t] = (f32x4){0.f, 0.f, 0.f, 0.f};

    const char* cW = (const char*)lsW;
    const int swz = (q & 7) << 4;
#pragma unroll
    for (int ks = 0; ks < 4; ++ks) {
        int koff = ks * 64 + khi * 16;
#pragma unroll
        for (int t = 0; t < 8; ++t) {
            short8v b = *(const short8v*)(cW + (t * 16 + q) * 256 + (koff ^ swz));
            acc[t] = __builtin_amdgcn_mfma_f32_16x16x32_bf16(af[ks].v, b, acc[t], 0, 0, 0);
        }
    }

    // D layout: col = q, row = khi*4 + r (within wave's 16-row sub-tile)
    const int rowbase = blockIdx.x * 128;
#pragma unroll
    for (int t = 0; t < 8; ++t) {
#pragma unroll
        for (int r = 0; r < 4; ++r) {
            int ro = rowbase + w * 16 + khi * 4 + r;
            if (ro < Nn) mapped[ro * D + t * 16 + q] = __float2bfloat16(acc[t][r]);
        }
    }
}

// ---- fused: bias + CSR gather-reduce + expmap + proj + mobius + proj ----
// 16-lane groups: 4 rows per wave, lane l owns dims (l&15)*8..+8 of group l>>4
__global__ __launch_bounds__(256) void k_aggfin(
    const uint4* __restrict__ mapped4, const int2* __restrict__ sedge,
    const int* __restrict__ rowptr, const float* __restrict__ bias,
    float* __restrict__ out, int Nn)
{
    const int tid = threadIdx.x;
    const int w = tid >> 6, l = tid & 63;
    const int g = l >> 4, q = l & 15;
    const int row = blockIdx.x * 16 + w * 4 + g;

    // bias point: identical computation in each 16-lane group
    float4 rb0 = *reinterpret_cast<const float4*>(bias + q * 8);
    float4 rb1 = *reinterpret_cast<const float4*>(bias + q * 8 + 4);
    float bn2 = rb0.x * rb0.x + rb0.y * rb0.y + rb0.z * rb0.z + rb0.w * rb0.w
              + rb1.x * rb1.x + rb1.y * rb1.y + rb1.z * rb1.z + rb1.w * rb1.w;
#pragma unroll
    for (int o = 8; o > 0; o >>= 1) bn2 += __shfl_xor(bn2, o, 64);
    float bn = fmaxf(sqrtf(bn2), FEPS);
    float bt = fast_tanh_clamped(bn);
    float bs = __fdividef(bt, bn);
    float ben2 = bs * bs * bn2;
    float bpn = fmaxf(sqrtf(ben2), FEPS);
    float bps = fminf(1.f, __fdividef(1.f - PROJ_EPS, bpn));
    float bsc = bs * bps;
    float y2 = bps * bps * ben2;
    float bj[8] = { rb0.x * bsc, rb0.y * bsc, rb0.z * bsc, rb0.w * bsc,
                    rb1.x * bsc, rb1.y * bsc, rb1.z * bsc, rb1.w * bsc };

    if (row >= Nn) return;
    int beg = rowptr[row], end = rowptr[row + 1];

    float acc[8] = {0.f, 0.f, 0.f, 0.f, 0.f, 0.f, 0.f, 0.f};
    int e = beg;
    for (; e + 1 < end; e += 2) {
        int2 d0 = sedge[e];
        int2 d1 = sedge[e + 1];
        uint4 u0 = mapped4[(size_t)d0.x * 16 + q];
        uint4 u1 = mapped4[(size_t)d1.x * 16 + q];
        float v0 = __int_as_float(d0.y), v1 = __int_as_float(d1.y);
        acc[0] += v0 * bf_lo(u0.x); acc[1] += v0 * bf_hi(u0.x);
        acc[2] += v0 * bf_lo(u0.y); acc[3] += v0 * bf_hi(u0.y);
        acc[4] += v0 * bf_lo(u0.z); acc[5] += v0 * bf_hi(u0.z);
        acc[6] += v0 * bf_lo(u0.w); acc[7] += v0 * bf_hi(u0.w);
        acc[0] += v1 * bf_lo(u1.x); acc[1] += v1 * bf_hi(u1.x);
        acc[2] += v1 * bf_lo(u1.y); acc[3] += v1 * bf_hi(u1.y);
        acc[4] += v1 * bf_lo(u1.z); acc[5] += v1 * bf_hi(u1.z);
        acc[6] += v1 * bf_lo(u1.w); acc[7] += v1 * bf_hi(u1.w);
    }
    if (e < end) {
        int2 d0 = sedge[e];
        uint4 u0 = mapped4[(size_t)d0.x * 16 + q];
        float v0 = __int_as_float(d0.y);
        acc[0] += v0 * bf_lo(u0.x); acc[1] += v0 * bf_hi(u0.x);
        acc[2] += v0 * bf_lo(u0.y); acc[3] += v0 * bf_hi(u0.y);
        acc[4] += v0 * bf_lo(u0.z); acc[5] += v0 * bf_hi(u0.z);
        acc[6] += v0 * bf_lo(u0.w); acc[7] += v0 * bf_hi(u0.w);
    }

    // dual 16-lane reduction: n2 = |a|^2, ab = a.b
    float n2 = 0.f, ab = 0.f;
#pragma unroll
    for (int j = 0; j < 8; ++j) { n2 += acc[j] * acc[j]; ab += acc[j] * bj[j]; }
#pragma unroll
    for (int o = 8; o > 0; o >>= 1) {
        n2 += __shfl_xor(n2, o, 64);
        ab += __shfl_xor(ab, o, 64);
    }

    // exp_map_zero + projection (group-uniform scalars)
    float n = fmaxf(sqrtf(n2), FEPS);
    float t = fast_tanh_clamped(n);
    float s = __fdividef(t, n);
    float en2 = s * s * n2;
    float pn = fmaxf(sqrtf(en2), FEPS);
    float ps = fminf(1.f, __fdividef(1.f - PROJ_EPS, pn));
    float hs = s * ps;
    float x2 = ps * ps * en2;

    // mobius_addition + final projection, |z|^2 analytic
    float xy = hs * ab;
    float cA = 1.f + 2.f * xy + y2;
    float cB = 1.f - x2;
    float den = fmaxf(1.f + 2.f * xy + x2 * y2, FEPS);
    float inv = __fdividef(1.f, den);
    float zn2 = inv * inv * (cA * cA * x2 + 2.f * cA * cB * xy + cB * cB * y2);
    float zn = fmaxf(sqrtf(zn2), FEPS);
    float zs = fminf(1.f, __fdividef(1.f - PROJ_EPS, zn));
    float f = inv * zs;
    float chs = cA * hs * f, cBf = cB * f;

    float4 o0 = make_float4(chs * acc[0] + cBf * bj[0], chs * acc[1] + cBf * bj[1],
                            chs * acc[2] + cBf * bj[2], chs * acc[3] + cBf * bj[3]);
    float4 o1 = make_float4(chs * acc[4] + cBf * bj[4], chs * acc[5] + cBf * bj[5],
                            chs * acc[6] + cBf * bj[6], chs * acc[7] + cBf * bj[7]);
    *reinterpret_cast<float4*>(out + (size_t)row * D + q * 8) = o0;
    *reinterpret_cast<float4*>(out + (size_t)row * D + q * 8 + 4) = o1;
}

extern "C" void kernel_launch(void* const* d_in, const int* in_sizes, int n_in,
                              void* d_out, int out_size, void* d_ws, size_t ws_size,
                              hipStream_t stream) {
    const float* x    = (const float*)d_in[0];
    const float* W    = (const float*)d_in[1];
    const float* bias = (const float*)d_in[2];
    const float* val  = (const float*)d_in[3];
    const int*   rowi = (const int*)d_in[4];
    const int*   coli = (const int*)d_in[5];
    const int N = in_sizes[0] / D;
    const int E = in_sizes[3];

    // ws layout (~32 MB)
    char* ws = (char*)d_ws;
    int*   cnt    = (int*)ws;                         // N*4
    int*   rowptr = (int*)(ws + 400000);              // (N+1)*4
    int*   bsum   = (int*)(ws + 800512);              // 128*4
    int*   bsumx  = (int*)(ws + 801024);              // 128*4
    int*   cursor = (int*)(ws + 801536);              // N*4
    int2*  sedge  = (int2*)(ws + 1201536);            // E*8
    __hip_bfloat16* mapped = (__hip_bfloat16*)(ws + 1201536 + (size_t)E * 8);  // N*D*2
    float* out = (float*)d_out;

    hipMemsetAsync(cnt, 0, (size_t)N * sizeof(int), stream);
    k_hist<<<(E + 511) / 512, 512, 0, stream>>>(rowi, cnt, E);

    int nb = (N + 1023) / 1024;
    k_scan1<<<nb, 256, 0, stream>>>(cnt, rowptr, bsum, N);
    k_scan2<<<1, 128, 0, stream>>>(bsum, bsumx, nb);
    k_scan3<<<(N + 255) / 256, 256, 0, stream>>>(rowptr, bsumx, cursor, N, E);

    const int GB = (N + 127) / 128;     // gemm blocks (128 rows each)
    const int SB = 256;                 // scatter blocks (overlap with gemm)
    k_gemm_scatter<<<GB + SB, 512, 0, stream>>>(x, W, mapped, N, rowi, coli, val,
                                                cursor, sedge, E, GB, SB);

    k_aggfin<<<(N + 15) / 16, 256, 0, stream>>>((const uint4*)mapped, sedge, rowptr,
                                                bias, out, N);
}